// Round 8
// baseline (484.180 us; speedup 1.0000x reference)
//
#include <hip/hip_runtime.h>
#include <math.h>
#include <limits.h>

#define N_NODES 50000
#define N_EDGES 800000
#define N_GRAPHS 64
#define IN_CH 128
#define EMB 64
#define POOL_CHUNK 16   // 50000 = 16 * 3125 exactly
#define CPAD 32         // counts padded to one per 128B line
#define NSLICE 8        // channel slices; slice s -> XCD s via blockIdx%8 heuristic
#define SLICE_CH 8      // channels per slice (EMB / NSLICE)

// ---------- init: padded counts=0, total=0, pool accumulators ----------
__global__ void init_k(int* counts, int* total, int* gmax, float* gsum, int* cnt) {
    int i = blockIdx.x * blockDim.x + threadIdx.x;
    if (i < N_NODES * CPAD) counts[i] = 0;
    if (i == 0) *total = 0;
    if (i < N_GRAPHS * EMB) { gmax[i] = INT_MIN; gsum[i] = 0.f; }
    if (i < N_GRAPHS) cnt[i] = 0;
}

// ---------- histogram: in-degree count; returned old value = stable slot ----------
__global__ void hist_k(const int* __restrict__ dst, int* counts,
                       int* __restrict__ slot_in) {
    int e = blockIdx.x * blockDim.x + threadIdx.x;
    if (e >= N_EDGES) return;
    slot_in[e] = atomicAdd(&counts[(size_t)dst[e] * CPAD], 1);
}

// ---------- CSR range allocation: wave-scan + one atomic per wave ----------
__global__ void alloc_k(const int* __restrict__ counts, int* __restrict__ row_start,
                        int* __restrict__ row_end, int* total) {
    int i = blockIdx.x * blockDim.x + threadIdx.x;
    int lane = threadIdx.x & 63;
    int c = (i < N_NODES) ? counts[(size_t)i * CPAD] : 0;
    int inc = c;
    for (int off = 1; off < 64; off <<= 1) {
        int v = __shfl_up(inc, off);
        if (lane >= off) inc += v;
    }
    int base;
    if (lane == 63) base = atomicAdd(total, inc);
    base = __shfl(base, 63);
    int excl = base + inc - c;
    if (i < N_NODES) { row_start[i] = excl; row_end[i] = excl + c; }
}

// ---------- scatter edges into CSR slots (atomic-free); store (src, raw w) ----------
__global__ void scatter_k(const int* __restrict__ src, const int* __restrict__ dst,
                          const float* __restrict__ w, const int* __restrict__ slot_in,
                          const int* __restrict__ row_start, int2* __restrict__ csr) {
    int e = blockIdx.x * blockDim.x + threadIdx.x;
    if (e >= N_EDGES) return;
    int d = dst[e];
    int slot = row_start[d] + slot_in[e];
    csr[slot] = make_int2(src[e], __float_as_int(w[e]));
}

// ---------- per-node weighted degree (wave reduction over CSR range) -> dinv ----------
__global__ __launch_bounds__(256) void deg_dinv_k(const int2* __restrict__ csr,
                                                  const int* __restrict__ row_start,
                                                  const int* __restrict__ row_end,
                                                  float* __restrict__ dinv) {
    int node = (blockIdx.x * blockDim.x + threadIdx.x) >> 6;
    int lane = threadIdx.x & 63;
    if (node >= N_NODES) return;
    int beg = row_start[node], end = row_end[node];
    float s = 0.f;
    for (int i = beg + lane; i < end; i += 64) s += __int_as_float(csr[i].y);
    for (int off = 32; off > 0; off >>= 1) s += __shfl_down(s, off);
    if (lane == 0) {
        float d = 1.0f + s;  // self-loop weight 1
        dinv[node] = d > 0.f ? rsqrtf(d) : 0.f;
    }
}

// ---------- rewrite csr.y: raw w -> norm = dinv[s] * w * dinv[d] ----------
__global__ __launch_bounds__(256) void normfix_k(int2* __restrict__ csr,
                                                 const int* __restrict__ row_start,
                                                 const int* __restrict__ row_end,
                                                 const float* __restrict__ dinv) {
    int node = (blockIdx.x * blockDim.x + threadIdx.x) >> 6;
    int lane = threadIdx.x & 63;
    if (node >= N_NODES) return;
    int beg = row_start[node], end = row_end[node];
    float dd = dinv[node];
    for (int i = beg + lane; i < end; i += 64) {
        int2 r = csr[i];
        float nm = dinv[r.x] * __int_as_float(r.y) * dd;
        csr[i] = make_int2(r.x, __float_as_int(nm));
    }
}

// ---------- h = A @ W : LDS-tiled; OUTPUT IN SLICED LAYOUT T[slice][node][8] ----------
template<int K>
__global__ __launch_bounds__(256) void gemm_k(const float* __restrict__ A,
                                              const float* __restrict__ W,
                                              float* __restrict__ T) {
    __shared__ float Al[64 * K];
    __shared__ float Wl[K * EMB];
    int tid = threadIdx.x;
    long rowBase = (long)blockIdx.x * 64;
    int validRows = (int)min((long)64, (long)N_NODES - rowBase);

    const float4* Ag = (const float4*)(A + rowBase * K);
    for (int i = tid; i < validRows * (K / 4); i += 256) {
        int r = i / (K / 4), kc = i % (K / 4);
        float4 v = Ag[(long)r * (K / 4) + kc];
        *(float4*)&Al[r * K + 4 * (kc ^ (r & 3))] = v;
    }
    const float4* Wg = (const float4*)W;
    float4* Wl4 = (float4*)Wl;
    for (int i = tid; i < K * EMB / 4; i += 256) Wl4[i] = Wg[i];
    __syncthreads();

    int tc = tid & 15, tr = tid >> 4;
    int r0 = tr * 4, c0 = tc * 4;
    float acc[4][4] = {};
#pragma unroll 2
    for (int k = 0; k < K; k += 4) {
        int kc = k >> 2;
        float4 a[4], w[4];
#pragma unroll
        for (int i = 0; i < 4; ++i)
            a[i] = *(const float4*)&Al[(r0 + i) * K + 4 * (kc ^ i)];
#pragma unroll
        for (int j = 0; j < 4; ++j)
            w[j] = *(const float4*)&Wl[(k + j) * EMB + c0];
#pragma unroll
        for (int i = 0; i < 4; ++i) {
            const float* ai = (const float*)&a[i];
#pragma unroll
            for (int kk = 0; kk < 4; ++kk) {
                float av = ai[kk];
                const float* wk = (const float*)&w[kk];
#pragma unroll
                for (int j = 0; j < 4; ++j) acc[i][j] += av * wk[j];
            }
        }
    }
    // sliced store: slice = c0/8, offset in 8-ch chunk = c0%8 (0 or 4)
    long sliceOff = (long)(tc >> 1) * N_NODES * SLICE_CH + (c0 & 7);
#pragma unroll
    for (int i = 0; i < 4; ++i) {
        long row = rowBase + r0 + i;
        if (row < N_NODES)
            *(float4*)&T[sliceOff + row * SLICE_CH] =
                make_float4(acc[i][0], acc[i][1], acc[i][2], acc[i][3]);
    }
}

// ---------- fused aggregation, XCD-sliced ----------
// slice = blockIdx%8 -> pinned to one XCD (round-robin dispatch heuristic);
// per-XCD working set = 1.6MB slice -> L2-resident gathers.
// wave = 8 nodes x 8 channels; out written in standard [node][64] layout.
__global__ __launch_bounds__(256) void fused_agg_k(const float* __restrict__ T,
                                                   const int2* __restrict__ csr,
                                                   const int* __restrict__ row_start,
                                                   const int* __restrict__ row_end,
                                                   const float* __restrict__ dinv,
                                                   const float* __restrict__ b,
                                                   float* __restrict__ out) {
    int slice = blockIdx.x & 7;
    int nodeBlk = blockIdx.x >> 3;              // 32 nodes per block
    int lane = threadIdx.x & 63;
    int wv = threadIdx.x >> 6;
    int grp = lane >> 3;                        // node within wave (0..7)
    int ch = lane & 7;                          // channel within slice
    int node = nodeBlk * 32 + wv * 8 + grp;
    if (node >= N_NODES) return;
    const float* Ts = T + (size_t)slice * N_NODES * SLICE_CH;
    float di = dinv[node];
    float acc = di * di * Ts[(size_t)node * SLICE_CH + ch] + b[slice * SLICE_CH + ch];
    int e = row_start[node];
    int end = row_end[node];
    for (; e + 3 < end; e += 4) {
        int2 r0 = csr[e], r1 = csr[e + 1], r2 = csr[e + 2], r3 = csr[e + 3];
        float v0 = Ts[(size_t)r0.x * SLICE_CH + ch];
        float v1 = Ts[(size_t)r1.x * SLICE_CH + ch];
        float v2 = Ts[(size_t)r2.x * SLICE_CH + ch];
        float v3 = Ts[(size_t)r3.x * SLICE_CH + ch];
        acc += __int_as_float(r0.y) * v0;
        acc += __int_as_float(r1.y) * v1;
        acc += __int_as_float(r2.y) * v2;
        acc += __int_as_float(r3.y) * v3;
    }
    for (; e < end; ++e) {
        int2 r = csr[e];
        acc += __int_as_float(r.y) * Ts[(size_t)r.x * SLICE_CH + ch];
    }
    out[(size_t)node * EMB + slice * SLICE_CH + ch] = tanhf(acc);
}

// ---------- pooling ----------
__device__ inline int f2ord(float x) {
    int bb = __float_as_int(x);
    return bb >= 0 ? bb : (bb ^ 0x7fffffff);
}
__device__ inline float ord2f(int k) {
    return __int_as_float(k >= 0 ? k : (k ^ 0x7fffffff));
}

// wave = 16 contiguous nodes (batch sorted); lane = channel.
__global__ __launch_bounds__(256) void pool_k(const float* __restrict__ h,
                                              const int* __restrict__ batch,
                                              int* gmax, float* gsum, int* cnt) {
    int wave = (blockIdx.x * blockDim.x + threadIdx.x) >> 6;
    int lane = threadIdx.x & 63;
    int start = wave * POOL_CHUNK;
    if (start >= N_NODES) return;
    int bsel = (lane < POOL_CHUNK) ? batch[start + lane] : 0;
    float v[POOL_CHUNK];
#pragma unroll
    for (int i = 0; i < POOL_CHUNK; ++i)
        v[i] = h[(long)(start + i) * EMB + lane];
    int curg = __shfl(bsel, 0);
    float mx = -INFINITY, sm = 0.f;
    int ct = 0;
#pragma unroll
    for (int i = 0; i < POOL_CHUNK; ++i) {
        int g = __shfl(bsel, i);
        if (g != curg) {
            atomicMax(&gmax[curg * EMB + lane], f2ord(mx));
            atomicAdd(&gsum[curg * EMB + lane], sm);
            if (lane == 0) atomicAdd(&cnt[curg], ct);
            curg = g; mx = -INFINITY; sm = 0.f; ct = 0;
        }
        mx = fmaxf(mx, v[i]);
        sm += v[i];
        ++ct;
    }
    atomicMax(&gmax[curg * EMB + lane], f2ord(mx));
    atomicAdd(&gsum[curg * EMB + lane], sm);
    if (lane == 0) atomicAdd(&cnt[curg], ct);
}

__global__ void final_k(const int* __restrict__ gmax, const float* __restrict__ gsum,
                        const int* __restrict__ cnt, const float* __restrict__ Wout,
                        const float* __restrict__ bout, float* __restrict__ out) {
    int g = threadIdx.x;
    if (g >= N_GRAPHS) return;
    float c = fmaxf((float)cnt[g], 1.0f);
    float acc = bout[0];
    for (int ch = 0; ch < EMB; ++ch) {
        acc += ord2f(gmax[g * EMB + ch]) * Wout[ch]
             + (gsum[g * EMB + ch] / c) * Wout[EMB + ch];
    }
    out[g] = acc;
}

extern "C" void kernel_launch(void* const* d_in, const int* in_sizes, int n_in,
                              void* d_out, int out_size, void* d_ws, size_t ws_size,
                              hipStream_t stream) {
    const float* x         = (const float*)d_in[0];
    const int*   edge_idx  = (const int*)d_in[1];
    const float* edge_attr = (const float*)d_in[2];
    const int*   batch     = (const int*)d_in[3];
    const float* W0 = (const float*)d_in[4];
    const float* b0 = (const float*)d_in[5];
    const float* W1 = (const float*)d_in[6];
    const float* b1 = (const float*)d_in[7];
    const float* W2 = (const float*)d_in[8];
    const float* b2 = (const float*)d_in[9];
    const float* W3 = (const float*)d_in[10];
    const float* b3 = (const float*)d_in[11];
    const float* Wout = (const float*)d_in[12];
    const float* bout = (const float*)d_in[13];
    float* out = (float*)d_out;

    const int* src = edge_idx;            // edge_index[0]
    const int* dst = edge_idx + N_EDGES;  // edge_index[1]

    // workspace layout (~43 MB)
    char* ws = (char*)d_ws;
    float* dinv      = (float*)ws; ws += (size_t)N_NODES * sizeof(float);
    int*   counts    = (int*)ws;   ws += (size_t)N_NODES * CPAD * sizeof(int);
    int*   row_start = (int*)ws;   ws += (size_t)N_NODES * sizeof(int);
    int*   row_end   = (int*)ws;   ws += (size_t)N_NODES * sizeof(int);
    int*   slot_in   = (int*)ws;   ws += (size_t)N_EDGES * sizeof(int);
    int*   total     = (int*)ws;   ws += 4 * sizeof(int);  // keep 16B alignment
    int2*  csr       = (int2*)ws;  ws += (size_t)N_EDGES * sizeof(int2);
    float* T         = (float*)ws; ws += (size_t)N_NODES * EMB * sizeof(float);  // sliced gather table
    float* bufH      = (float*)ws; ws += (size_t)N_NODES * EMB * sizeof(float);  // standard layout
    int*   gmax      = (int*)ws;   ws += N_GRAPHS * EMB * sizeof(int);
    float* gsum      = (float*)ws; ws += N_GRAPHS * EMB * sizeof(float);
    int*   cnt       = (int*)ws;   ws += N_GRAPHS * sizeof(int);

    const int nodeB = (N_NODES + 255) / 256;
    const int edgeB = (N_EDGES + 255) / 256;
    const int waveB = (N_NODES * 64 + 255) / 256;
    const int gemmB = (N_NODES + 63) / 64;
    const int initB = (N_NODES * CPAD + 255) / 256;
    const int aggB  = ((N_NODES + 31) / 32) * NSLICE;  // 1563 node-blocks x 8 slices

    // CSR + norm precompute (shared by all 4 layers)
    init_k<<<initB, 256, 0, stream>>>(counts, total, gmax, gsum, cnt);
    hist_k<<<edgeB, 256, 0, stream>>>(dst, counts, slot_in);
    alloc_k<<<nodeB, 256, 0, stream>>>(counts, row_start, row_end, total);
    scatter_k<<<edgeB, 256, 0, stream>>>(src, dst, edge_attr, slot_in, row_start, csr);
    deg_dinv_k<<<waveB, 256, 0, stream>>>(csr, row_start, row_end, dinv);
    normfix_k<<<waveB, 256, 0, stream>>>(csr, row_start, row_end, dinv);

    const float* Wl[4] = {W0, W1, W2, W3};
    const float* bl[4] = {b0, b1, b2, b3};
    for (int l = 0; l < 4; ++l) {
        if (l == 0) gemm_k<IN_CH><<<gemmB, 256, 0, stream>>>(x, Wl[0], T);
        else        gemm_k<EMB>  <<<gemmB, 256, 0, stream>>>(bufH, Wl[l], T);
        fused_agg_k<<<aggB, 256, 0, stream>>>(T, csr, row_start, row_end, dinv, bl[l], bufH);
    }

    pool_k<<<(((N_NODES + POOL_CHUNK - 1) / POOL_CHUNK) * 64 + 255) / 256, 256, 0, stream>>>(
        bufH, batch, gmax, gsum, cnt);
    final_k<<<1, 64, 0, stream>>>(gmax, gsum, cnt, Wout, bout, out);
}